// Round 4
// baseline (189.583 us; speedup 1.0000x reference)
//
#include <hip/hip_runtime.h>
#include <math.h>

#define NANCH 896
#define MAXD 64
#define NS 14   // 896 / 64 slots per lane (max; active slot count nsc <= 14)

// ONE WAVE per batch, one wave per block, no barriers.
// Round-4 = Round-2's PROVEN per-iteration machinery (shfl butterfly argmax,
// shfl fast-path broadcast, shfl partner exchange) + ONE new element: active
// anchors compacted into LDS once at setup, so every NMS iteration scans
// nsc ~= ceil(nact/64) ~= 7 slots instead of 14. All R3 DPP/key-packing/
// LDS-transpose machinery (the unproven failure suspects) is removed.
__global__ __launch_bounds__(64, 2) void blaze_wave_kernel(
    const float* __restrict__ raw_boxes,   // [B,896,16]
    const float* __restrict__ raw_scores,  // [B,896]
    const float* __restrict__ anchors,     // [896,4]
    const float* __restrict__ tmat,        // [B,8]
    const int* __restrict__ hptr,
    const int* __restrict__ wptr,
    float* __restrict__ out,               // [B,64,17]
    int B)
{
    __shared__ float4 cbox[NANCH];            // compacted decoded boxes
    __shared__ float  cscore[NANCH];          // compacted scores
    __shared__ unsigned short cidx[NANCH];    // compacted -> original anchor idx
    __shared__ float  sdet[17];               // stuck-fill broadcast

    const int lane = threadIdx.x;             // 0..63
    const int b    = blockIdx.x;
    if (b >= B) return;

    const float* rb = raw_boxes  + (size_t)b * (NANCH * 16);
    const float* rs = raw_scores + (size_t)b * NANCH;
    const float inv = 1.f / 128.f;

    // ---- uniform per-batch params in the up-front load burst ----
    const float* M = tmat + (size_t)b * 8;
    const float m0 = M[0], m1 = M[1], m3 = M[3];
    const float m4 = M[4], m5 = M[5], m7 = M[7];
    const float hf = (float)(*hptr);
    const float wf = (float)(*wptr);

    // ---- Phase 1: ALL score loads issued back-to-back ----
    float xv[NS];
#pragma unroll
    for (int j = 0; j < NS; ++j) xv[j] = rs[lane + 64 * j];

    // ---- Phase 2: box/anchor loads gated by SIGN only (sigmoid>=0.5 <=> x>=0;
    //      NaN -> inactive both sides). Inactive lanes alias row 0's line. ----
    bool  act[NS];
    float4 r0v[NS], anv[NS];
#pragma unroll
    for (int j = 0; j < NS; ++j) {
        act[j] = (xv[j] >= 0.f);
        const int a2 = act[j] ? (lane + 64 * j) : 0;
        r0v[j] = *(const float4*)(rb + a2 * 16);
        anv[j] = *(const float4*)(anchors + a2 * 4);
    }

    // ---- sigmoid overlaps the in-flight box loads ----
    float sv[NS];
#pragma unroll
    for (int j = 0; j < NS; ++j) {
        float x = fminf(fmaxf(xv[j], -100.f), 100.f);
        sv[j] = 1.f / (1.f + expf(-x));
    }

    // ---- decode + COMPACT active anchors into LDS (ascending anchor order:
    //      slot-major then lane prefix => compacted pos is order-isomorphic
    //      to original anchor index, preserving the argmax tie-break) ----
    int base = 0;
#pragma unroll
    for (int j = 0; j < NS; ++j) {
        float xc = r0v[j].x * inv * anv[j].z + anv[j].x;
        float yc = r0v[j].y * inv * anv[j].w + anv[j].y;
        float ww = r0v[j].z * inv * anv[j].z;
        float hh = r0v[j].w * inv * anv[j].w;
        float y0 = yc - hh * 0.5f, x0 = xc - ww * 0.5f;
        float y1 = yc + hh * 0.5f, x1 = xc + ww * 0.5f;
        unsigned long long m = __ballot(act[j]);
        int pos = base + __popcll(m & ((1ull << lane) - 1ull));
        if (act[j]) {
            cbox[pos]   = make_float4(y0, x0, y1, x1);
            cscore[pos] = sv[j];
            cidx[pos]   = (unsigned short)(lane + 64 * j);
        }
        base += __popcll(m);
    }
    const int nact = base;                  // wave-uniform
    const int nsc  = (nact + 63) >> 6;      // wave-uniform active slot count

    // ---- read compacted entries back into per-lane slot registers ----
    float cb0[NS], cb1[NS], cb2[NS], cb3[NS], car[NS], rem[NS];
    int   corig[NS];
#pragma unroll
    for (int k = 0; k < NS; ++k) {
        rem[k] = -1.f;
        if (k < nsc) {                       // wave-uniform guard
            int p = k * 64 + lane;
            bool v = (p < nact);
            int pc = v ? p : 0;
            float4 bb = cbox[pc];
            float sc  = cscore[pc];
            corig[k]  = (int)cidx[pc];
            cb0[k] = bb.x; cb1[k] = bb.y; cb2[k] = bb.z; cb3[k] = bb.w;
            car[k] = fmaxf(bb.z - bb.x, 0.f) * fmaxf(bb.w - bb.y, 0.f);
            if (v) rem[k] = sc;
        }
    }

    float* ob = out + (size_t)b * (MAXD * 17);
    // x-channels: {1,3,4,6,8,10,12,14} -> bitmask 0x555A; partner = c^1
    const bool isx = (lane < 16) && ((0x555Au >> lane) & 1u);

    int iter = 0;
    while (true) {
        // ---- argmax(rem) over nsc slots, first-compacted-pos tie-break ----
        float bv = -2.f; int bi = 1 << 30;
#pragma unroll
        for (int j = 0; j < NS; ++j) if (j < nsc) {
            if (rem[j] > bv) { bv = rem[j]; bi = j * 64 + lane; }
        }
#pragma unroll
        for (int s2 = 32; s2 >= 1; s2 >>= 1) {
            float ov = __shfl_xor(bv, s2, 64);
            int   oi = __shfl_xor(bi, s2, 64);
            if (ov > bv || (ov == bv && oi < bi)) { bv = ov; bi = oi; }
        }

        if (bv <= 0.f) {                    // nothing active left -> zero fill
            int n = (MAXD - iter) * 17;
            float* op = ob + iter * 17;
            for (int e = lane; e < n; e += 64) op[e] = 0.f;
            break;
        }

        // ---- best box: one broadcast LDS read (uniform address) ----
        float4 bb = cbox[bi];
        const float bby0 = bb.x, bbx0 = bb.y, bby1 = bb.z, bbx1 = bb.w;
        const float a1 = fmaxf(bby1 - bby0, 0.f) * fmaxf(bbx1 - bbx0, 0.f);

        float acc[16];
#pragma unroll
        for (int c = 0; c < 16; ++c) acc[c] = 0.f;
        float wsum = 0.f;
        bool anyov = false;

        // ---- overlap scan over nsc compacted slots ----
#pragma unroll
        for (int j = 0; j < NS; ++j) if (j < nsc) {
            float yA = fmaxf(bby0, cb0[j]);
            float xA = fmaxf(bbx0, cb1[j]);
            float yB = fminf(bby1, cb2[j]);
            float xB = fminf(bbx1, cb3[j]);
            float inter = fmaxf(yB - yA, 0.f) * fmaxf(xB - xA, 0.f);
            if (inter > 0.f) {
                float iou = inter / fmaxf(a1 + car[j] - inter, 1e-6f);
                if (iou > 0.3f && rem[j] > 0.f) {
                    anyov = true;
                    float wj = rem[j];          // rem>0 ==> rem == score
                    rem[j] = -1.f;
                    wsum += wj;
                    acc[0] += cb0[j] * wj; acc[1] += cb1[j] * wj;
                    acc[2] += cb2[j] * wj; acc[3] += cb3[j] * wj;
                    // keypoints refetched only for overlapped boxes (rare)
                    const int orig = corig[j];
                    float4 an = *(const float4*)(anchors + orig * 4);
                    const float* rp = rb + orig * 16;
                    float4 r1 = *(const float4*)(rp + 4);
                    float4 r2 = *(const float4*)(rp + 8);
                    float4 r3 = *(const float4*)(rp + 12);
                    acc[4]  += (r1.x * inv * an.z + an.x) * wj;
                    acc[5]  += (r1.y * inv * an.w + an.y) * wj;
                    acc[6]  += (r1.z * inv * an.z + an.x) * wj;
                    acc[7]  += (r1.w * inv * an.w + an.y) * wj;
                    acc[8]  += (r2.x * inv * an.z + an.x) * wj;
                    acc[9]  += (r2.y * inv * an.w + an.y) * wj;
                    acc[10] += (r2.z * inv * an.z + an.x) * wj;
                    acc[11] += (r2.w * inv * an.w + an.y) * wj;
                    acc[12] += (r3.x * inv * an.z + an.x) * wj;
                    acc[13] += (r3.y * inv * an.w + an.y) * wj;
                    acc[14] += (r3.z * inv * an.z + an.x) * wj;
                    acc[15] += (r3.w * inv * an.w + an.y) * wj;
                }
            }
        }

        const unsigned long long mm = __ballot(anyov);
        const bool stuck = (mm == 0ull);

        float q, dnm;
        if (stuck) {
            q = 0.f; dnm = 1e-6f;            // reference: blend of zeros
        } else if (__popcll(mm) == 1) {
            // FAST PATH: one contributing lane -> broadcast its partials.
            // Bit-exact vs butterfly: all other lanes hold +0 and x+0==x.
            const int src = (int)__ffsll((long long)mm) - 1;
            float t = __shfl(acc[0], src, 64);
#pragma unroll
            for (int c = 1; c < 16; ++c) {
                float tc = __shfl(acc[c], src, 64);
                t = (lane == c) ? tc : t;
            }
            q   = t;
            dnm = fmaxf(__shfl(wsum, src, 64), 1e-6f);
        } else {
            // general path (rare): identical butterfly tree as prior rounds
#pragma unroll
            for (int s2 = 32; s2 >= 1; s2 >>= 1) {
                wsum += __shfl_xor(wsum, s2, 64);
#pragma unroll
                for (int c = 0; c < 16; ++c) acc[c] += __shfl_xor(acc[c], s2, 64);
            }
            float t = acc[0];
#pragma unroll
            for (int c2 = 1; c2 < 16; ++c2) t = (lane == c2) ? acc[c2] : t;
            q = t; dnm = fmaxf(wsum, 1e-6f);
        }

        q = q / dnm;                                   // ONE divide per lane
        const float p = __shfl(q, lane ^ 1, 64);       // x/y partner channel
        const float detc = (lane >= 16) ? bv
                         : (isx ? (q * m0 + p * m1 + m3) * wf
                                : (p * m4 + q * m5 + m7) * hf);

        if (stuck) {
            // det identical for all remaining rows; lane c holds det[c]
            if (lane < 17) sdet[lane] = detc;
            int n = (MAXD - iter) * 17;
            float* op = ob + iter * 17;
            int c = lane % 17;
            for (int e = lane; e < n; e += 64) {
                op[e] = sdet[c];
                c += 13; if (c >= 17) c -= 17;         // (e+64) % 17
            }
            break;
        } else {
            if (lane < 17) ob[iter * 17 + lane] = detc;
            ++iter;
            if (iter == MAXD) break;
        }
    }
}

extern "C" void kernel_launch(void* const* d_in, const int* in_sizes, int n_in,
                              void* d_out, int out_size, void* d_ws, size_t ws_size,
                              hipStream_t stream) {
    (void)n_in; (void)out_size; (void)d_ws; (void)ws_size;
    const float* raw_boxes  = (const float*)d_in[0];
    const float* raw_scores = (const float*)d_in[1];
    const float* anchors    = (const float*)d_in[2];
    const float* tmat       = (const float*)d_in[3];
    const int*   hptr       = (const int*)d_in[4];
    const int*   wptr       = (const int*)d_in[5];
    float* out = (float*)d_out;

    const int B = in_sizes[0] / (NANCH * 16);
    blaze_wave_kernel<<<B, 64, 0, stream>>>(raw_boxes, raw_scores, anchors,
                                            tmat, hptr, wptr, out, B);
}

// Round 5
// 185.973 us; speedup vs baseline: 1.0194x; 1.0194x over previous
//
#include <hip/hip_runtime.h>
#include <math.h>

#define NANCH 896
#define MAXD 64
#define NS 14   // 896 / 64 max slots per lane

// Templated NMS loop: NSLOT is COMPILE-TIME so both hot scans (argmax, IoU)
// are straight-line fully-unrolled code with cross-slot ILP -- no per-slot
// runtime guards (R4's regression: branchy guard regions serialized the
// dependent min/max chains at latency instead of throughput).
template <int NSLOT>
__device__ __forceinline__ void nms_loop(
    const int lane, const int nact,
    const float4* __restrict__ cbox, const float* __restrict__ cscore,
    const unsigned short* __restrict__ cidx, float* __restrict__ sdet,
    const float* __restrict__ rb, const float* __restrict__ anchors,
    const float m0, const float m1, const float m3,
    const float m4, const float m5, const float m7,
    const float hf, const float wf, float* __restrict__ ob)
{
    const float inv = 1.f / 128.f;

    // ---- readback compacted entries into per-lane slot registers ----
    float cb0[NSLOT], cb1[NSLOT], cb2[NSLOT], cb3[NSLOT], car[NSLOT], rem[NSLOT];
    int   corig[NSLOT];
#pragma unroll
    for (int k = 0; k < NSLOT; ++k) {
        int p = k * 64 + lane;
        bool v = (p < nact);
        int pc = v ? p : 0;
        float4 bb = cbox[pc];
        cb0[k] = bb.x; cb1[k] = bb.y; cb2[k] = bb.z; cb3[k] = bb.w;
        car[k] = fmaxf(bb.z - bb.x, 0.f) * fmaxf(bb.w - bb.y, 0.f);
        corig[k] = (int)cidx[pc];
        rem[k] = v ? cscore[pc] : -1.f;
    }

    // x-channels: {1,3,4,6,8,10,12,14} -> bitmask 0x555A; partner = c^1
    const bool isx = (lane < 16) && ((0x555Au >> lane) & 1u);

    int iter = 0;
    while (true) {
        // ---- argmax(rem), first-compacted-pos tie-break (straight-line) ----
        float bv = -2.f; int bi = 1 << 30;
#pragma unroll
        for (int j = 0; j < NSLOT; ++j) {
            if (rem[j] > bv) { bv = rem[j]; bi = j * 64 + lane; }
        }
#pragma unroll
        for (int s2 = 32; s2 >= 1; s2 >>= 1) {
            float ov = __shfl_xor(bv, s2, 64);
            int   oi = __shfl_xor(bi, s2, 64);
            if (ov > bv || (ov == bv && oi < bi)) { bv = ov; bi = oi; }
        }

        if (bv <= 0.f) {                    // nothing active left -> zero fill
            int n = (MAXD - iter) * 17;
            float* op = ob + iter * 17;
            for (int e = lane; e < n; e += 64) op[e] = 0.f;
            break;
        }

        // ---- best box: one broadcast LDS read (uniform address) ----
        float4 bb = cbox[bi];
        const float bby0 = bb.x, bbx0 = bb.y, bby1 = bb.z, bbx1 = bb.w;
        const float a1 = fmaxf(bby1 - bby0, 0.f) * fmaxf(bbx1 - bbx0, 0.f);

        float acc[16];
#pragma unroll
        for (int c = 0; c < 16; ++c) acc[c] = 0.f;
        float wsum = 0.f;
        bool anyov = false;

        // ---- overlap scan (straight-line, full cross-slot ILP) ----
#pragma unroll
        for (int j = 0; j < NSLOT; ++j) {
            float yA = fmaxf(bby0, cb0[j]);
            float xA = fmaxf(bbx0, cb1[j]);
            float yB = fminf(bby1, cb2[j]);
            float xB = fminf(bbx1, cb3[j]);
            float inter = fmaxf(yB - yA, 0.f) * fmaxf(xB - xA, 0.f);
            if (inter > 0.f) {
                float iou = inter / fmaxf(a1 + car[j] - inter, 1e-6f);
                if (iou > 0.3f && rem[j] > 0.f) {
                    anyov = true;
                    float wj = rem[j];          // rem>0 ==> rem == score
                    rem[j] = -1.f;
                    wsum += wj;
                    acc[0] += cb0[j] * wj; acc[1] += cb1[j] * wj;
                    acc[2] += cb2[j] * wj; acc[3] += cb3[j] * wj;
                    // keypoints refetched only for overlapped boxes (rare)
                    const int orig = corig[j];
                    float4 an = *(const float4*)(anchors + orig * 4);
                    const float* rp = rb + orig * 16;
                    float4 r1 = *(const float4*)(rp + 4);
                    float4 r2 = *(const float4*)(rp + 8);
                    float4 r3 = *(const float4*)(rp + 12);
                    acc[4]  += (r1.x * inv * an.z + an.x) * wj;
                    acc[5]  += (r1.y * inv * an.w + an.y) * wj;
                    acc[6]  += (r1.z * inv * an.z + an.x) * wj;
                    acc[7]  += (r1.w * inv * an.w + an.y) * wj;
                    acc[8]  += (r2.x * inv * an.z + an.x) * wj;
                    acc[9]  += (r2.y * inv * an.w + an.y) * wj;
                    acc[10] += (r2.z * inv * an.z + an.x) * wj;
                    acc[11] += (r2.w * inv * an.w + an.y) * wj;
                    acc[12] += (r3.x * inv * an.z + an.x) * wj;
                    acc[13] += (r3.y * inv * an.w + an.y) * wj;
                    acc[14] += (r3.z * inv * an.z + an.x) * wj;
                    acc[15] += (r3.w * inv * an.w + an.y) * wj;
                }
            }
        }

        const unsigned long long mm = __ballot(anyov);
        const bool stuck = (mm == 0ull);

        float q, dnm;
        if (stuck) {
            q = 0.f; dnm = 1e-6f;            // reference: blend of zeros
        } else if (__popcll(mm) == 1) {
            // FAST PATH: one contributing lane -> broadcast its partials.
            // Bit-exact vs butterfly: all other lanes hold +0 and x+0==x.
            const int src = (int)__ffsll((long long)mm) - 1;
            float t = __shfl(acc[0], src, 64);
#pragma unroll
            for (int c = 1; c < 16; ++c) {
                float tc = __shfl(acc[c], src, 64);
                t = (lane == c) ? tc : t;
            }
            q   = t;
            dnm = fmaxf(__shfl(wsum, src, 64), 1e-6f);
        } else {
            // general path (rare): identical butterfly tree as prior rounds
#pragma unroll
            for (int s2 = 32; s2 >= 1; s2 >>= 1) {
                wsum += __shfl_xor(wsum, s2, 64);
#pragma unroll
                for (int c = 0; c < 16; ++c) acc[c] += __shfl_xor(acc[c], s2, 64);
            }
            float t = acc[0];
#pragma unroll
            for (int c2 = 1; c2 < 16; ++c2) t = (lane == c2) ? acc[c2] : t;
            q = t; dnm = fmaxf(wsum, 1e-6f);
        }

        q = q / dnm;                                   // ONE divide per lane
        const float p = __shfl(q, lane ^ 1, 64);       // x/y partner channel
        const float detc = (lane >= 16) ? bv
                         : (isx ? (q * m0 + p * m1 + m3) * wf
                                : (p * m4 + q * m5 + m7) * hf);

        if (stuck) {
            // det identical for all remaining rows; lane c holds det[c]
            if (lane < 17) sdet[lane] = detc;
            int n = (MAXD - iter) * 17;
            float* op = ob + iter * 17;
            int c = lane % 17;
            for (int e = lane; e < n; e += 64) {
                op[e] = sdet[c];
                c += 13; if (c >= 17) c -= 17;         // (e+64) % 17
            }
            break;
        } else {
            if (lane < 17) ob[iter * 17 + lane] = detc;
            ++iter;
            if (iter == MAXD) break;
        }
    }
}

// ONE WAVE per batch. Setup (loads, sigmoid, decode, compaction) identical to
// the proven R4 kernel; the NMS loop is dispatched to a compile-time NSLOT
// specialization so the hot scans are guard-free straight-line code.
__global__ __launch_bounds__(64, 2) void blaze_wave_kernel(
    const float* __restrict__ raw_boxes,   // [B,896,16]
    const float* __restrict__ raw_scores,  // [B,896]
    const float* __restrict__ anchors,     // [896,4]
    const float* __restrict__ tmat,        // [B,8]
    const int* __restrict__ hptr,
    const int* __restrict__ wptr,
    float* __restrict__ out,               // [B,64,17]
    int B)
{
    __shared__ float4 cbox[NANCH];            // compacted decoded boxes
    __shared__ float  cscore[NANCH];          // compacted scores
    __shared__ unsigned short cidx[NANCH];    // compacted -> original anchor idx
    __shared__ float  sdet[17];               // stuck-fill broadcast

    const int lane = threadIdx.x;             // 0..63
    const int b    = blockIdx.x;
    if (b >= B) return;

    const float* rb = raw_boxes  + (size_t)b * (NANCH * 16);
    const float* rs = raw_scores + (size_t)b * NANCH;
    const float inv = 1.f / 128.f;

    // ---- uniform per-batch params in the up-front load burst ----
    const float* M = tmat + (size_t)b * 8;
    const float m0 = M[0], m1 = M[1], m3 = M[3];
    const float m4 = M[4], m5 = M[5], m7 = M[7];
    const float hf = (float)(*hptr);
    const float wf = (float)(*wptr);

    // ---- Phase 1: ALL score loads issued back-to-back ----
    float xv[NS];
#pragma unroll
    for (int j = 0; j < NS; ++j) xv[j] = rs[lane + 64 * j];

    // ---- Phase 2: box/anchor loads gated by SIGN only (sigmoid>=0.5 <=> x>=0;
    //      NaN -> inactive both sides). Inactive lanes alias row 0's line. ----
    bool  act[NS];
    float4 r0v[NS], anv[NS];
#pragma unroll
    for (int j = 0; j < NS; ++j) {
        act[j] = (xv[j] >= 0.f);
        const int a2 = act[j] ? (lane + 64 * j) : 0;
        r0v[j] = *(const float4*)(rb + a2 * 16);
        anv[j] = *(const float4*)(anchors + a2 * 4);
    }

    // ---- sigmoid overlaps the in-flight box loads ----
    float sv[NS];
#pragma unroll
    for (int j = 0; j < NS; ++j) {
        float x = fminf(fmaxf(xv[j], -100.f), 100.f);
        sv[j] = 1.f / (1.f + expf(-x));
    }

    // ---- decode + COMPACT active anchors into LDS (ascending anchor order:
    //      compacted pos is order-isomorphic to anchor index -> exact tiebreak) ----
    int base = 0;
#pragma unroll
    for (int j = 0; j < NS; ++j) {
        float xc = r0v[j].x * inv * anv[j].z + anv[j].x;
        float yc = r0v[j].y * inv * anv[j].w + anv[j].y;
        float ww = r0v[j].z * inv * anv[j].z;
        float hh = r0v[j].w * inv * anv[j].w;
        float y0 = yc - hh * 0.5f, x0 = xc - ww * 0.5f;
        float y1 = yc + hh * 0.5f, x1 = xc + ww * 0.5f;
        unsigned long long m = __ballot(act[j]);
        int pos = base + __popcll(m & ((1ull << lane) - 1ull));
        if (act[j]) {
            cbox[pos]   = make_float4(y0, x0, y1, x1);
            cscore[pos] = sv[j];
            cidx[pos]   = (unsigned short)(lane + 64 * j);
        }
        base += __popcll(m);
    }
    const int nact = base;                  // wave-uniform
    const int nsc  = (nact + 63) >> 6;      // wave-uniform active slot count

    float* ob = out + (size_t)b * (MAXD * 17);

    // ---- one wave-uniform dispatch to a compile-time slot count ----
    if (nsc <= 7)
        nms_loop<7>(lane, nact, cbox, cscore, cidx, sdet, rb, anchors,
                    m0, m1, m3, m4, m5, m7, hf, wf, ob);
    else if (nsc <= 8)
        nms_loop<8>(lane, nact, cbox, cscore, cidx, sdet, rb, anchors,
                    m0, m1, m3, m4, m5, m7, hf, wf, ob);
    else if (nsc <= 10)
        nms_loop<10>(lane, nact, cbox, cscore, cidx, sdet, rb, anchors,
                     m0, m1, m3, m4, m5, m7, hf, wf, ob);
    else
        nms_loop<14>(lane, nact, cbox, cscore, cidx, sdet, rb, anchors,
                     m0, m1, m3, m4, m5, m7, hf, wf, ob);
}

extern "C" void kernel_launch(void* const* d_in, const int* in_sizes, int n_in,
                              void* d_out, int out_size, void* d_ws, size_t ws_size,
                              hipStream_t stream) {
    (void)n_in; (void)out_size; (void)d_ws; (void)ws_size;
    const float* raw_boxes  = (const float*)d_in[0];
    const float* raw_scores = (const float*)d_in[1];
    const float* anchors    = (const float*)d_in[2];
    const float* tmat       = (const float*)d_in[3];
    const int*   hptr       = (const int*)d_in[4];
    const int*   wptr       = (const int*)d_in[5];
    float* out = (float*)d_out;

    const int B = in_sizes[0] / (NANCH * 16);
    blaze_wave_kernel<<<B, 64, 0, stream>>>(raw_boxes, raw_scores, anchors,
                                            tmat, hptr, wptr, out, B);
}